// Round 15
// baseline (124.713 us; speedup 1.0000x reference)
//
#include <hip/hip_runtime.h>
#include <hip/hip_bf16.h>
#include <hip/hip_fp16.h>
#include <math.h>

// Problem constants
#define DIM   512
#define NTR   16384
#define NT    8192
#define NCLS  16
#define NROWS (NTR + NT)   // 24576 projection rows

// simmain tiling: wave owns one 16-i tile; block = 8 waves (512 thr) = 128
// i's, one 1024-j chunk staged once in LDS. Grid (NT/128, JS) = (64, 16).
#define JS     16                  // j-splits (33 MB atomic flush; 66 MB = +20 us, r8/r11)
#define JC     (NTR / JS)          // 1024 j per chunk
#define STEPS  (JC / 32)           // 32 K-steps (32 j each) per wave
#define NSTEPS (NTR / 32)          // 512 global K-steps

#define PROJ_BLOCKS (NROWS / 16)          // 1536 (16 rows/block, 4/wave)
#define PREP_BLOCKS ((NSTEPS * 64) / 256) // 128 (y-bake + accumulator zeroing)

// ws layout (floats): kq [24576][2] | numer [8192][16] | denom [8192] |
//                     yfh (bf16 A-frag plane, single plane)
#define WS_KQ_F    (NROWS * 2)           // 49152
#define WS_NUMER_F (NT * NCLS)           // 131072
#define WS_DENOM_F (NT)                  // 8192
#define WS_ZERO_V4 ((WS_NUMER_F + WS_DENOM_F) / 4)   // 34816 float4s

typedef __attribute__((ext_vector_type(8))) short short8;
typedef __attribute__((ext_vector_type(4))) float f32x4;
typedef __attribute__((ext_vector_type(4))) unsigned int uint4v;
typedef _Float16 h2 __attribute__((ext_vector_type(2)));

static __device__ __forceinline__ short f2bf(float f) {   // RNE (prep only)
    unsigned u = __float_as_uint(f);
    return (short)((u + 0x7FFFu + ((u >> 16) & 1u)) >> 16);
}
// Pack 2 positive floats to bf16x2 (round-half-up): 2 adds + 1 v_perm.
static __device__ __forceinline__ unsigned pkbf(float a, float b) {
    unsigned ua = __float_as_uint(a) + 0x8000u;
    unsigned ub = __float_as_uint(b) + 0x8000u;
    return __builtin_amdgcn_perm(ub, ua, 0x07060302);   // (bf(b)<<16)|bf(a)
}
// Pack 2 floats to fp16x2, RNE (staging only).
static __device__ __forceinline__ unsigned pkh(float a, float b) {
    unsigned la = (unsigned)__half_as_ushort(__float2half(a));
    unsigned hb = (unsigned)__half_as_ushort(__float2half(b));
    return la | (hb << 16);
}
// logit = dot(qpk, kj) with fp16 inputs, fp32 accumulate.
static __device__ __forceinline__ float dot2h(h2 q, unsigned kj) {
    const h2 k = __builtin_bit_cast(h2, kj);
#if __has_builtin(__builtin_amdgcn_fdot2)
    return __builtin_amdgcn_fdot2(q, k, 0.0f, false);
#else
    return (float)q.x * (float)k.x + (float)q.y * (float)k.y;
#endif
}

// ---------------------------------------------------------------------------
// Kernel 1 (fused prep): blocks [0,1536) = projection (4 rows/wave, 8
// independent loads + 8 parallel shuffle-reduce chains); blocks [1536,1664) =
// ytr^T bf16 bake in MFMA A-frag order (single plane) + zeroing of
// numer/denom. NO cross-block fences (round 6: device-scope fences cost
// ~full-L2-writeback per block on multi-XCD CDNA4).
// ---------------------------------------------------------------------------
__global__ __launch_bounds__(256) void prep_kernel(
    const float* __restrict__ xtr, const float* __restrict__ xt,
    const float* __restrict__ A, const float* __restrict__ ytr,
    float* __restrict__ kq, short* __restrict__ yfh,
    float* __restrict__ zbase)
{
    const int b = blockIdx.x;
    if (b < PROJ_BLOCKS) {
        const int wave = threadIdx.x >> 6;
        const int lane = threadIdx.x & 63;
        const int row0 = b * 16 + wave * 4;

        const float* xp[4];
#pragma unroll
        for (int r = 0; r < 4; ++r) {
            const int row = row0 + r;
            xp[r] = (row < NTR) ? (xtr + (size_t)row * DIM)
                                : (xt + (size_t)(row - NTR) * DIM);
        }
        float a0[4] = {0.f, 0.f, 0.f, 0.f}, a1[4] = {0.f, 0.f, 0.f, 0.f};
#pragma unroll
        for (int t = 0; t < 2; ++t) {
            const int d = lane * 4 + t * 256;
            float4 A0 = *(const float4*)(A + 2 * d);       // A[d..d+1][0..1]
            float4 A1 = *(const float4*)(A + 2 * d + 4);   // A[d+2..d+3][0..1]
#pragma unroll
            for (int r = 0; r < 4; ++r) {
                float4 u = *(const float4*)(xp[r] + d);
                a0[r] += u.x * A0.x + u.y * A0.z + u.z * A1.x + u.w * A1.z;
                a1[r] += u.x * A0.y + u.y * A0.w + u.z * A1.y + u.w * A1.w;
            }
        }
#pragma unroll
        for (int off = 32; off >= 1; off >>= 1) {
#pragma unroll
            for (int r = 0; r < 4; ++r) {
                a0[r] += __shfl_xor(a0[r], off, 64);
                a1[r] += __shfl_xor(a1[r], off, 64);
            }
        }
        if (lane == 0) {
            *(float4*)(kq + row0 * 2)     = make_float4(a0[0], a1[0], a0[1], a1[1]);
            *(float4*)(kq + row0 * 2 + 4) = make_float4(a0[2], a1[2], a0[3], a1[3]);
        }
    } else {
        const int idx = (b - PROJ_BLOCKS) * 256 + threadIdx.x;  // 0..32767
        // zero numer+denom (34816 float4s over 32768 threads)
        float4 z = make_float4(0.f, 0.f, 0.f, 0.f);
        for (int p = idx; p < WS_ZERO_V4; p += PREP_BLOCKS * 256)
            ((float4*)zbase)[p] = z;

        const int l   = idx & 63;
        const int s   = idx >> 6;
        const int cls = l & 15;
        const int jb  = s * 32 + (l >> 4) * 8;
        short8 hi;
#pragma unroll
        for (int t = 0; t < 8; ++t)
            hi[t] = f2bf(ytr[(size_t)(jb + t) * NCLS + cls]);
        ((short8*)yfh)[idx] = hi;
    }
}

// ---------------------------------------------------------------------------
// Kernel 2: main. Grid (NT/128, JS) = (64, 16) = 1024 blocks of 512 threads.
// All-LDS K-loop (r13/r14) with fp16-packed k (r15): the block stages its
// k-chunk as fp16x2 (4 KB; RNE-converted from fp32 kq during staging) and
// its y-chunk (32 KB bf16 A-frags). r14 accounting: LDS data-return was the
// dominant pipe (~67%), with the 4 k b128s costing 48 of 60 cyc/wave-step —
// fp16 k halves that (8-j octet = 32 B = 2 b128) and v_dot2_f32_f16 does
// each logit in one VALU op (fp32 accumulate; q fp16-RNE once per kernel;
// peaked-row e errors cancel in the numer/denom ratio).
// Per step: 1 y b128 + 2 k b128 (LDS 36 cyc), 8 dot2 + 8 raw v_exp_f32 +
// v_perm pack, 2 MFMAs (Y@E -> numer, Ones@E -> denom). Fire-and-forget
// atomic flush; separate finalize kernel (round 6: fences = ~L2-writeback
// per block).
// ---------------------------------------------------------------------------
__global__ __launch_bounds__(512) void simmain_kernel(
    const float* __restrict__ kq, const short* __restrict__ yfh,
    float* __restrict__ numer, float* __restrict__ denom)
{
    __shared__ unsigned ksp[JC];         // 4 KB fp16x2 k-chunk (1 dword per j)
    __shared__ short8  ys[STEPS * 64];   // 32 KB bf16 y-frags (A-op order)

    const int tid  = threadIdx.x;        // 0..511
    const int wave = tid >> 6;           // 0..7
    const int lane = tid & 63;
    const int j0   = blockIdx.y * JC;

    const int i0   = (blockIdx.x * 8 + wave) * 16;
    const int m    = lane & 15;
    const int quad = lane >> 4;

    // q: load fp32, scale by log2(e), pack to fp16x2 once
    const float2 qv = *(const float2*)(kq + 2 * (NTR + i0 + m));
    const h2 qpk = __builtin_bit_cast(h2,
        pkh(qv.x * 1.4426950408889634f, qv.y * 1.4426950408889634f));

    {   // stage k (512 float4 -> 1024 fp16x2 dwords) + y (2048 float4)
        const float4 kv = ((const float4*)(kq + 2 * j0))[tid];   // 2 j's
        ksp[2 * tid]     = pkh(kv.x, kv.y);
        ksp[2 * tid + 1] = pkh(kv.z, kv.w);
        const float4* ysrc = (const float4*)(yfh + (size_t)blockIdx.y * (STEPS * 64) * 8);
        float4* ydst = (float4*)ys;
#pragma unroll
        for (int p = 0; p < 4; ++p)
            ydst[tid + 512 * p] = ysrc[tid + 512 * p];
    }
    __syncthreads();

    f32x4 acc  = {0.f, 0.f, 0.f, 0.f};
    f32x4 acc2 = {0.f, 0.f, 0.f, 0.f};
    short8 ones;
#pragma unroll
    for (int t = 0; t < 8; ++t) ones[t] = (short)0x3F80;   // bf16 1.0

    const short8* __restrict__ yls = ys + lane;                  // + s*64 per step
    const uint4v* __restrict__ kx  = ((const uint4v*)ksp) + quad * 2;  // quad's octet

#pragma unroll 4
    for (int s = 0; s < STEPS; ++s) {
        const short8 yh = yls[s * 64];          // lane-contiguous ds_read_b128
        const uint4v kA = kx[s * 8];            // j octet lo (4 packed k's)
        const uint4v kB = kx[s * 8 + 1];        // j octet hi

        const float e0 = __builtin_amdgcn_exp2f(dot2h(qpk, kA[0]));
        const float e1 = __builtin_amdgcn_exp2f(dot2h(qpk, kA[1]));
        const float e2 = __builtin_amdgcn_exp2f(dot2h(qpk, kA[2]));
        const float e3 = __builtin_amdgcn_exp2f(dot2h(qpk, kA[3]));
        const float e4 = __builtin_amdgcn_exp2f(dot2h(qpk, kB[0]));
        const float e5 = __builtin_amdgcn_exp2f(dot2h(qpk, kB[1]));
        const float e6 = __builtin_amdgcn_exp2f(dot2h(qpk, kB[2]));
        const float e7 = __builtin_amdgcn_exp2f(dot2h(qpk, kB[3]));

        uint4v ep;
        ep[0] = pkbf(e0, e1); ep[1] = pkbf(e2, e3);
        ep[2] = pkbf(e4, e5); ep[3] = pkbf(e6, e7);
        const short8 eb = __builtin_bit_cast(short8, ep);

        acc  = __builtin_amdgcn_mfma_f32_16x16x32_bf16(yh,   eb, acc,  0, 0, 0);
        acc2 = __builtin_amdgcn_mfma_f32_16x16x32_bf16(ones, eb, acc2, 0, 0, 0);
    }

    // Flush: lane holds numer[i0+m][quad*4+r] = acc[r]; dsum(i0+m) = acc2[*]
    float* nrow = numer + (size_t)(i0 + m) * NCLS + quad * 4;
#pragma unroll
    for (int r = 0; r < 4; ++r)
        atomicAdd(nrow + r, acc[r]);
    if (quad == 0)
        atomicAdd(denom + i0 + m, acc2[0]);
}

// ---------------------------------------------------------------------------
// Kernel 3: finalize — divide numerators by softmax denominator.
// ---------------------------------------------------------------------------
__global__ __launch_bounds__(256) void finalize_kernel(
    const float* __restrict__ numer, const float* __restrict__ denom,
    float* __restrict__ out)
{
    const int idx = blockIdx.x * 256 + threadIdx.x;   // < NT*NCLS
    out[idx] = numer[idx] / denom[idx >> 4];
}

// ---------------------------------------------------------------------------
extern "C" void kernel_launch(void* const* d_in, const int* in_sizes, int n_in,
                              void* d_out, int out_size, void* d_ws, size_t ws_size,
                              hipStream_t stream)
{
    const float* xtr = (const float*)d_in[0];   // [16384][512]
    const float* ytr = (const float*)d_in[1];   // [16384][16]
    const float* xt  = (const float*)d_in[2];   // [8192][512]
    const float* A   = (const float*)d_in[3];   // [512][2]
    float* out = (float*)d_out;                 // [8192][16]

    float* kq    = (float*)d_ws;                       // 49152 floats
    float* numer = kq + WS_KQ_F;                       // 131072 floats
    float* denom = numer + WS_NUMER_F;                 // 8192 floats
    short* yfh   = (short*)(denom + WS_DENOM_F);       // 262144 shorts (512 KB)

    prep_kernel<<<PROJ_BLOCKS + PREP_BLOCKS, 256, 0, stream>>>(
        xtr, xt, A, ytr, kq, yfh, numer);
    simmain_kernel<<<dim3(NT / 128, JS), 512, 0, stream>>>(
        kq, yfh, numer, denom);
    finalize_kernel<<<(NT * NCLS) / 256, 256, 0, stream>>>(numer, denom, out);
}